// Round 1
// baseline (42.448 us; speedup 1.0000x reference)
//
#include <hip/hip_runtime.h>

// LIF soma forward: x [T=64, B=128, N=4096] f32, tau_m [1] f32 -> spikes [T,B,N] f32.
// Sequential scan over T, independent across B*N. Memory-bound streaming kernel.

#define U_THRESHOLD_F (-0.055f)
#define U_REST_F      (-0.07f)

constexpr int  T_STEPS = 64;
constexpr long BN      = 128L * 4096L;      // elements per timestep
constexpr long STRIDE4 = BN / 4;            // float4 elements per timestep (131072)

__global__ __launch_bounds__(256) void lif_soma_fwd(const float4* __restrict__ x,
                                                    const float* __restrict__ tau_m,
                                                    float4* __restrict__ out) {
    const long idx = (long)blockIdx.x * blockDim.x + threadIdx.x;   // 0 .. STRIDE4-1
    const float inv_tau = 1.0f / tau_m[0];

    const float4* xp = x + idx;
    float4*       op = out + idx;

    float4 h = make_float4(U_REST_F, U_REST_F, U_REST_F, U_REST_F);

    float4 xt = xp[0];

#pragma unroll
    for (int t = 0; t < T_STEPS; ++t) {
        float4 xn;
        if (t + 1 < T_STEPS) xn = xp[(long)(t + 1) * STRIDE4];

        float4 o;
        // component x
        {
            float u = h.x + inv_tau * ((U_REST_F - h.x) + xt.x);
            float v = u - U_THRESHOLD_F;
            float s = (v >= 0.0f) ? 1.0f : 0.0f;
            o.x = s;
            h.x = (v >= 0.0f) ? U_REST_F : u;
        }
        // component y
        {
            float u = h.y + inv_tau * ((U_REST_F - h.y) + xt.y);
            float v = u - U_THRESHOLD_F;
            float s = (v >= 0.0f) ? 1.0f : 0.0f;
            o.y = s;
            h.y = (v >= 0.0f) ? U_REST_F : u;
        }
        // component z
        {
            float u = h.z + inv_tau * ((U_REST_F - h.z) + xt.z);
            float v = u - U_THRESHOLD_F;
            float s = (v >= 0.0f) ? 1.0f : 0.0f;
            o.z = s;
            h.z = (v >= 0.0f) ? U_REST_F : u;
        }
        // component w
        {
            float u = h.w + inv_tau * ((U_REST_F - h.w) + xt.w);
            float v = u - U_THRESHOLD_F;
            float s = (v >= 0.0f) ? 1.0f : 0.0f;
            o.w = s;
            h.w = (v >= 0.0f) ? U_REST_F : u;
        }

        op[(long)t * STRIDE4] = o;
        xt = xn;
    }
}

extern "C" void kernel_launch(void* const* d_in, const int* in_sizes, int n_in,
                              void* d_out, int out_size, void* d_ws, size_t ws_size,
                              hipStream_t stream) {
    const float4* x     = (const float4*)d_in[0];
    const float*  tau_m = (const float*)d_in[1];
    float4*       out   = (float4*)d_out;

    const int threads = 256;
    const int blocks  = (int)(STRIDE4 / threads);   // 512
    lif_soma_fwd<<<blocks, threads, 0, stream>>>(x, tau_m, out);
}